// Round 14
// baseline (471.789 us; speedup 1.0000x reference)
//
#include <hip/hip_runtime.h>

typedef _Float16 half_t;
typedef __attribute__((ext_vector_type(8))) _Float16 half8;
typedef __attribute__((ext_vector_type(4))) float floatx4;

// ---------------------------------------------------------------------------
// Round 18: gemm = R15 exact (best: 64us L2, all restructuring neutral).
// ln_prep split: pure im2col (gather+cvt+ONE val stream, writes halved,
// no reduce/exp/LN) + chan_ss + pix_stats (R13-proven per-pixel mean/istd).
// LN applied inside gemm at j==0 (float4 lnw/lnb loads, transient regs,
// amortized over 9 K-steps); silu computed at j==8 from prefetched val.
// Gemm global reads halve (val replaces pn+sp).
// ---------------------------------------------------------------------------

#define RBF_SCALE 2.1019644f       // 1.75 * sqrt(log2 e)
#define RBF_G0   -4.2039288f       // RBF_SCALE * (-2)
#define RBF_2D    2.40224482f      // 2*sqrt(log2 e)
#define RBF_D2    1.44269504f      // log2 e
#define RBF_Q     0.13533528f      // e^-2
#define LOG2E     1.44269504f

// ---- per-pixel channel sums: S = sum_ch x, S2 = sum_ch x^2 ----
template<int C, int HW>
__global__ __launch_bounds__(256)
void chan_ss(const float* __restrict__ src, float2* __restrict__ ss)
{
    int idx = blockIdx.x * 256 + threadIdx.x;   // b*HW + hw (grid exact)
    int b = idx / HW, hw = idx - b * HW;
    const float* p = src + (long)b * C * HW + hw;
    float s = 0.f, s2 = 0.f;
    #pragma unroll 4
    for (int c = 0; c < C; ++c) {
        float v = p[(long)c * HW];
        s += v; s2 += v * v;
    }
    ss[idx] = make_float2(s, s2);
}

// ---- per-pixel LayerNorm stats from 3x3 window of channel sums ----
template<int IN, int H, int W>
__global__ __launch_bounds__(256)
void pix_stats(const float2* __restrict__ ss, float2* __restrict__ ms)
{
    const int HW = H * W;
    int idx = blockIdx.x * 256 + threadIdx.x;   // b*HW + hw (grid exact)
    int b = idx / HW, hw = idx - b * HW;
    int h = hw / W, w = hw - h * W;
    float s = 0.f, s2 = 0.f;
    #pragma unroll
    for (int dy = -1; dy <= 1; ++dy)
        #pragma unroll
        for (int dx = -1; dx <= 1; ++dx) {
            int y = h + dy, xx = w + dx;
            if (y >= 0 && y < H && xx >= 0 && xx < W) {
                float2 v = ss[(long)b * HW + y * W + xx];
                s += v.x; s2 += v.y;
            }
        }
    float mean = s / IN;
    float istd = rsqrtf(s2 / IN - mean * mean + 1e-5f);
    ms[idx] = make_float2(mean, istd);
}

// ---- pure im2col: patch gather -> val fp16 [pix][IN]; 16 pixels/block ----
// block: 16 consecutive-in-x pixels (same row; W%16==0). Wave wv handles
// pixels wv*4..wv*4+3 sequentially. Window [C][3][19] staged once.
template<int C, int H, int W>
__global__ __launch_bounds__(256)
void im2col(const float* __restrict__ x, half_t* __restrict__ val)
{
    const int HW = H * W, IN = C * 9;
    const int NL = (IN + 63) / 64;
    __shared__ float xw[C * 57];                 // [C][3][19], cols 0..17 used

    const int wv = threadIdx.x >> 6, lane = threadIdx.x & 63;
    const int pix0 = blockIdx.x * 16;
    const int b = pix0 / HW, hw0 = pix0 % HW;
    const int h = hw0 / W, x0 = hw0 % W;         // pixels x0..x0+15, same row
    const float* xb = x + (long)b * C * HW;

    for (int idx = threadIdx.x; idx < C * 54; idx += 256) {
        int ch = idx / 54, rem = idx - ch * 54;
        int dy = rem / 18, col = rem - dy * 18;
        int y = h + dy - 1, xx = x0 + col - 1;
        float v = 0.f;
        if (y >= 0 && y < H && xx >= 0 && xx < W)
            v = xb[(long)ch * HW + y * W + xx];
        xw[ch * 57 + dy * 19 + col] = v;
    }
    __syncthreads();

    int ga[NL];
    #pragma unroll
    for (int t = 0; t < NL; ++t) {
        int i = t * 64 + lane;
        if (i < IN) {
            int ch = i / 9, r = i - ch * 9;
            int dy = r / 3, dx = r - dy * 3;
            ga[t] = ch * 57 + dy * 19 + dx;
        } else ga[t] = 0;
    }

    #pragma unroll
    for (int p = 0; p < 4; ++p) {
        const int px = wv * 4 + p;               // 0..15
        const long base = (long)(pix0 + px) * IN;
        #pragma unroll
        for (int t = 0; t < NL; ++t) {
            int i = t * 64 + lane;
            if (i < IN) val[base + i] = (half_t)xw[ga[t] + px];
        }
    }
}

// ---- fp32 weights -> fp16 packed [step][OUT][64], XOR pre-swizzle ----
// step s -> iblk = s/9, j = s%9; packed col uu holds k-unit (uu>>3)^(o&7):
// i = iblk*64 + ((uu>>3)^(o&7))*8 + (uu&7); k = j*IN + i (j<8 Ws, j==8 Wb).
template<int IN, int OUT>
__global__ __launch_bounds__(256)
void conv_w(const float* __restrict__ Ws, const float* __restrict__ Wb,
            half_t* __restrict__ Wt)
{
    const int NIB = (IN + 63) / 64, NSTEP = NIB * 9;
    int idx = blockIdx.x * 256 + threadIdx.x;
    if (idx >= OUT * NSTEP * 64) return;
    int uu = idx & 63;
    int t = idx >> 6;
    int o = t % OUT;
    int s = t / OUT;
    int iblk = s / 9, j = s % 9;
    int ulin = (((uu >> 3) ^ (o & 7)) << 3) + (uu & 7);
    int i = iblk * 64 + ulin;
    float v = 0.f;
    if (i < IN)
        v = (j < 8) ? Ws[(long)o * IN * 8 + i * 8 + j] : Wb[(long)o * IN + i];
    Wt[idx] = (half_t)v;
}

// ---- fused LN + A-gen + MFMA GEMM (R15 loop; LN at j==0, silu at j==8) ----
// block: 64 pixels x (4*NB*16) outputs at yoff; wave wv: NB*16 outputs.
// B via global_load_lds (linear dest, pre-swizzled source). A swizzled writes.
// LDS XOR swizzle: 16B unit w at w ^ (row & 7), row stride 64 halfs.
template<int IN, int OUT, int HW, int NB, int SPLIT>
__global__ __launch_bounds__(256)
void kan_gemm(const half_t* __restrict__ val, const float2* __restrict__ ms,
              const float* __restrict__ lnw, const float* __restrict__ lnb,
              const half_t* __restrict__ Wt, float* __restrict__ out)
{
    const int NIB = (IN + 63) / 64;

    __shared__ half_t As[64 * 64];
    __shared__ half_t Bs[NB * 64 * 64];

    const int tid = threadIdx.x;
    const int row = tid >> 2, q = tid & 3;
    const int pix = blockIdx.x * 64 + row;
    const half_t* valrow = val + (long)pix * IN;

    const int wv = tid >> 6, lane = tid & 63;
    const int lr = lane & 15, lq = lane >> 4;
    const int u0 = (2 * q) ^ (row & 7);         // swizzled 16B units (A stage)
    const int u1 = (2 * q + 1) ^ (row & 7);
    const int yoff = blockIdx.y * (4 * NB * 16);

    const float2 msv = ms[pix];
    const float mean = msv.x, istd = msv.y;

    floatx4 acc[NB][4] = {};
    float r[16], u[16];
    half8 pf0, pf1;                              // global prefetch pair

    const int grpA = (blockIdx.z * NIB) / SPLIT;         // group-aligned split
    const int grpB = ((blockIdx.z + 1) * NIB) / SPLIT;
    const int s0 = grpA * 9, s1 = grpB * 9;

    int jg = 0, ibg = grpA;    // A-gen state: next step to generate

    // clamped-address global load (tail chunks: weights are zero there)
    auto ldglob = [&](int ib) {
        int i0 = ib * 64 + q * 16;
        const half_t* pp = valrow + ((i0 < IN) ? i0 : 0);
        pf0 = *(const half8*)pp;
        pf1 = *(const half8*)(pp + 8);
    };

    auto stageB = [&](int it) {
        const half_t* wsrc = Wt + (long)it * OUT * 64
                              + (long)(yoff + wv * NB * 16) * 64;
        #pragma unroll
        for (int c = 0; c < NB * 2; ++c) {
            __builtin_amdgcn_global_load_lds(
                (const __attribute__((address_space(1))) void*)(wsrc + c * 512 + lane * 8),
                (__attribute__((address_space(3))) void*)(&Bs[wv * NB * 1024 + c * 512]),
                16, 0, 0);
        }
    };

    auto genA = [&]() {
        if (jg < 8) {
            if (jg == 0) {
                // pf holds val(ibg): apply LN, init RBF recurrence
                int i0c = ibg * 64 + q * 16;
                int ic = (i0c < IN) ? i0c : 0;
                const float4* lwp = (const float4*)(lnw + ic);
                const float4* lbp = (const float4*)(lnb + ic);
                float lw[8], lb[8];
                *(float4*)&lw[0] = lwp[0]; *(float4*)&lw[4] = lwp[1];
                *(float4*)&lb[0] = lbp[0]; *(float4*)&lb[4] = lbp[1];
                #pragma unroll
                for (int kk = 0; kk < 8; ++kk) {
                    float v0 = (float)pf0[kk];
                    float pnv = fmaf((v0 - mean) * istd, lw[kk], lb[kk]) * RBF_SCALE;
                    pnv = fminf(12.f, fmaxf(-12.f, pnv));
                    float d0 = pnv - RBF_G0;
                    r[kk] = __builtin_amdgcn_exp2f(-(d0 * d0));
                    u[kk] = __builtin_amdgcn_exp2f(fmaf(RBF_2D, d0, -RBF_D2));
                }
                *(float4*)&lw[0] = lwp[2]; *(float4*)&lw[4] = lwp[3];
                *(float4*)&lb[0] = lbp[2]; *(float4*)&lb[4] = lbp[3];
                #pragma unroll
                for (int kk = 0; kk < 8; ++kk) {
                    float v1 = (float)pf1[kk];
                    float pnv = fmaf((v1 - mean) * istd, lw[kk], lb[kk]) * RBF_SCALE;
                    pnv = fminf(12.f, fmaxf(-12.f, pnv));
                    float d1 = pnv - RBF_G0;
                    r[kk + 8] = __builtin_amdgcn_exp2f(-(d1 * d1));
                    u[kk + 8] = __builtin_amdgcn_exp2f(fmaf(RBF_2D, d1, -RBF_D2));
                }
            }
            half8 a0, a1;
            #pragma unroll
            for (int kk = 0; kk < 8; ++kk) {
                a0[kk] = (half_t)r[kk];
                a1[kk] = (half_t)r[kk + 8];
            }
            *(half8*)&As[row * 64 + u0 * 8] = a0;
            *(half8*)&As[row * 64 + u1 * 8] = a1;
            if (jg < 7) {
                #pragma unroll
                for (int kk = 0; kk < 16; ++kk) { r[kk] *= u[kk]; u[kk] *= RBF_Q; }
            }
            if (jg == 7) ldglob(ibg);            // re-fetch val(ibg) for silu
        } else {
            // pf holds val(ibg): silu in-reg
            half8 a0, a1;
            #pragma unroll
            for (int kk = 0; kk < 8; ++kk) {
                float v0 = (float)pf0[kk];
                float v1 = (float)pf1[kk];
                a0[kk] = (half_t)(v0 * __builtin_amdgcn_rcpf(
                             1.f + __builtin_amdgcn_exp2f(-v0 * LOG2E)));
                a1[kk] = (half_t)(v1 * __builtin_amdgcn_rcpf(
                             1.f + __builtin_amdgcn_exp2f(-v1 * LOG2E)));
            }
            *(half8*)&As[row * 64 + u0 * 8] = a0;
            *(half8*)&As[row * 64 + u1 * 8] = a1;
            ldglob(ibg + 1);                     // prefetch next i-block's val
        }
        if (++jg == 9) { jg = 0; ++ibg; }
    };

    auto domfma = [&]() {
        __builtin_amdgcn_s_setprio(1);
        #pragma unroll
        for (int ks = 0; ks < 2; ++ks) {
            half8 af[4], bf[NB];
            #pragma unroll
            for (int mf = 0; mf < 4; ++mf) {
                int rr = mf * 16 + lr;
                af[mf] = *(const half8*)&As[rr * 64 + (((ks * 4 + lq) ^ (rr & 7)) * 8)];
            }
            #pragma unroll
            for (int nb = 0; nb < NB; ++nb) {
                int rr = wv * NB * 16 + nb * 16 + lr;
                bf[nb] = *(const half8*)&Bs[rr * 64 + (((ks * 4 + lq) ^ (rr & 7)) * 8)];
            }
            #pragma unroll
            for (int nb = 0; nb < NB; ++nb)
                #pragma unroll
                for (int mf = 0; mf < 4; ++mf)
                    acc[nb][mf] = __builtin_amdgcn_mfma_f32_16x16x32_f16(
                        bf[nb], af[mf], acc[nb][mf], 0, 0, 0);
        }
        __builtin_amdgcn_s_setprio(0);
    };

    // ---- prologue: prefetch val(grpA) ----
    ldglob(grpA);

    // ---- main loop: stage (async) + A-gen, barrier, MFMA ----
    for (int it = s0; it < s1; ++it) {
        __syncthreads();           // previous MFMA reads done
        stageB(it);                // async gload_lds -> Bs
        genA();                    // VALU + swizzled ds_write -> As
        __syncthreads();           // drain: As/Bs ready
        domfma();
    }

    // ---- epilogue: plain stores into z-partial slab ----
    const long zoff = (long)blockIdx.z * ((long)gridDim.x * 64) * OUT;
    #pragma unroll
    for (int nb = 0; nb < NB; ++nb)
    #pragma unroll
    for (int mf = 0; mf < 4; ++mf)
    #pragma unroll
    for (int reg = 0; reg < 4; ++reg) {
        int o  = yoff + wv * NB * 16 + nb * 16 + lq * 4 + reg;
        int p2 = blockIdx.x * 64 + mf * 16 + lr;
        int b2 = p2 / HW, hw2 = p2 % HW;
        out[zoff + ((long)b2 * OUT + o) * HW + hw2] = acc[nb][mf][reg];
    }
}

// ---- BatchNorm batch-stats over summed z-partials (bias folded in) ----
__launch_bounds__(256)
__global__ void bn_stats(const float* __restrict__ h, const float* __restrict__ bias,
                         int C, int HW, int B, int nz, float* __restrict__ sums)
{
    int c = blockIdx.y;
    float bbc = bias[c];
    long zstride = (long)B * C * HW;
    int total = B * HW;
    float s = 0.f, s2 = 0.f;
    for (int idx = blockIdx.x * 256 + threadIdx.x; idx < total; idx += 256 * gridDim.x) {
        int b = idx / HW, r = idx % HW;
        long base = ((long)b * C + c) * HW + r;
        float v = bbc;
        for (int z = 0; z < nz; ++z) v += h[z * zstride + base];
        s += v; s2 += v * v;
    }
    for (int off = 32; off > 0; off >>= 1) {
        s  += __shfl_down(s,  off, 64);
        s2 += __shfl_down(s2, off, 64);
    }
    __shared__ float rs[4], rs2[4];
    int lane = threadIdx.x & 63, wid = threadIdx.x >> 6;
    if (lane == 0) { rs[wid] = s; rs2[wid] = s2; }
    __syncthreads();
    if (threadIdx.x == 0) {
        atomicAdd(&sums[c],     rs[0] + rs[1] + rs[2] + rs[3]);
        atomicAdd(&sums[C + c], rs2[0] + rs2[1] + rs2[2] + rs2[3]);
    }
}

__launch_bounds__(256)
__global__ void bn_relu_pool(const float* __restrict__ h, const float* __restrict__ sums,
                             const float* __restrict__ bias,
                             const float* __restrict__ gamma, const float* __restrict__ beta,
                             float* __restrict__ out, int B, int C, int H, int W, int nz)
{
    int Ho = H / 2, Wo = W / 2;
    long total = (long)B * C * Ho * Wo;
    long idx = (long)blockIdx.x * 256 + threadIdx.x;
    if (idx >= total) return;
    int pw = idx % Wo; long t = idx / Wo;
    int ph = t % Ho; t /= Ho;
    int c = t % C; int b = (int)(t / C);

    float M = (float)B * H * W;
    float mean = sums[c] / M;
    float var  = sums[C + c] / M - mean * mean;
    float scale = gamma[c] * rsqrtf(var + 1e-5f);
    float shift = beta[c] - mean * scale + bias[c] * scale;  // fold conv bias

    long zstride = (long)B * C * H * W;
    const float* hp = h + ((long)b * C + c) * H * W;
    float m = 0.f;  // post-relu >= 0
    #pragma unroll
    for (int i = 0; i < 2; ++i)
        #pragma unroll
        for (int j = 0; j < 2; ++j) {
            long off = (2 * ph + i) * W + 2 * pw + j;
            float v = 0.f;
            for (int z = 0; z < nz; ++z) v += hp[z * zstride + off];
            v = v * scale + shift;
            m = fmaxf(m, v);
        }
    out[idx] = m;
}

extern "C" void kernel_launch(void* const* d_in, const int* in_sizes, int n_in,
                              void* d_out, int out_size, void* d_ws, size_t ws_size,
                              hipStream_t stream) {
    const float* x     = (const float*)d_in[0];
    const float* ln_w1 = (const float*)d_in[1];  const float* ln_b1 = (const float*)d_in[2];
    const float* Wb1   = (const float*)d_in[3];  const float* bb1   = (const float*)d_in[4];
    const float* Ws1   = (const float*)d_in[5];  const float* g1    = (const float*)d_in[6];
    const float* be1   = (const float*)d_in[7];
    const float* ln_w2 = (const float*)d_in[8];  const float* ln_b2 = (const float*)d_in[9];
    const float* Wb2   = (const float*)d_in[10]; const float* bb2   = (const float*)d_in[11];
    const float* Ws2   = (const float*)d_in[12]; const float* g2    = (const float*)d_in[13];
    const float* be2   = (const float*)d_in[14];
    const float* ln_w3 = (const float*)d_in[15]; const float* ln_b3 = (const float*)d_in[16];
    const float* Wb3   = (const float*)d_in[17]; const float* bb3   = (const float*)d_in[18];
    const float* Ws3   = (const float*)d_in[19]; const float* g3    = (const float*)d_in[20];
    const float* be3   = (const float*)d_in[21];

    const int B = 32;
    char* ws = (char*)d_ws;
    float*  convbuf = (float*)(ws + 0);              // 33,554,432 (z-partials L2/L3)
    float*  poolbuf = (float*)(ws + 33554432);       //  8,388,608
    float*  stats1  = (float*)(ws + 41943040);       //  2048 x3
    float*  stats2  = (float*)(ws + 41945088);
    float*  stats3  = (float*)(ws + 41947136);
    half_t* wt1     = (half_t*)(ws + 41949184);      //   221,184  (27 x 64 x 64)
    half_t* wt2     = (half_t*)(ws + 42170368);      // 1,327,104  (81 x 128 x 64)
    half_t* wt3     = (half_t*)(ws + 43497472);      // 5,308,416  (162 x 256 x 64)
    half_t* valbuf  = (half_t*)(ws + 48805888);      // 37,748,736 (max 131072x144)
    float2* ssbuf   = (float2*)(ws + 86554624);      //  1,048,576
    float2* msbuf   = (float2*)(ws + 87603200);      //  1,048,576
    // total: 88,651,776 B

    hipMemsetAsync(stats1, 0, 6144, stream);

    conv_w<144, 64><<<(64 * 27 * 64 + 255) / 256, 256, 0, stream>>>(Ws1, Wb1, wt1);
    conv_w<576, 128><<<(128 * 81 * 64 + 255) / 256, 256, 0, stream>>>(Ws2, Wb2, wt2);
    conv_w<1152, 256><<<(256 * 162 * 64 + 255) / 256, 256, 0, stream>>>(Ws3, Wb3, wt3);

    // ---------------- layer 1: C=16, H=W=64, OUT=64, NB=1, y=1, z=1 ---------
    {
        const int H = 64, W = 64, OUT = 64;
        int npix = B * H * W;                    // 131072
        chan_ss<16, H * W><<<npix / 256, 256, 0, stream>>>(x, ssbuf);
        pix_stats<144, H, W><<<npix / 256, 256, 0, stream>>>(ssbuf, msbuf);
        im2col<16, H, W><<<npix / 16, 256, 0, stream>>>(x, valbuf);
        kan_gemm<144, OUT, H * W, 1, 1><<<dim3(npix / 64, 1, 1), 256, 0, stream>>>(
            valbuf, msbuf, ln_w1, ln_b1, wt1, convbuf);
        bn_stats<<<dim3(64, OUT), 256, 0, stream>>>(convbuf, bb1, OUT, H * W, B, 1, stats1);
        long tot = (long)B * OUT * (H / 2) * (W / 2);
        bn_relu_pool<<<(tot + 255) / 256, 256, 0, stream>>>(
            convbuf, stats1, bb1, g1, be1, poolbuf, B, OUT, H, W, 1);
    }
    // ---------------- layer 2: C=64, H=W=32, OUT=128, NB=2, y=1, z=2 --------
    {
        const int H = 32, W = 32, OUT = 128;
        int npix = B * H * W;                    // 32768
        chan_ss<64, H * W><<<npix / 256, 256, 0, stream>>>(poolbuf, ssbuf);
        pix_stats<576, H, W><<<npix / 256, 256, 0, stream>>>(ssbuf, msbuf);
        im2col<64, H, W><<<npix / 16, 256, 0, stream>>>(poolbuf, valbuf);
        kan_gemm<576, OUT, H * W, 2, 2><<<dim3(npix / 64, 1, 2), 256, 0, stream>>>(
            valbuf, msbuf, ln_w2, ln_b2, wt2, convbuf);   // 2 x 16.8 MB partials
        bn_stats<<<dim3(16, OUT), 256, 0, stream>>>(convbuf, bb2, OUT, H * W, B, 2, stats2);
        long tot = (long)B * OUT * (H / 2) * (W / 2);
        bn_relu_pool<<<(tot + 255) / 256, 256, 0, stream>>>(
            convbuf, stats2, bb2, g2, be2, poolbuf, B, OUT, H, W, 2);
    }
    // ---------------- layer 3: C=128, H=W=16, OUT=256, NB=2, y=2, z=4 -------
    {
        const int H = 16, W = 16, OUT = 256;
        int npix = B * H * W;                    // 8192
        chan_ss<128, H * W><<<npix / 256, 256, 0, stream>>>(poolbuf, ssbuf);
        pix_stats<1152, H, W><<<npix / 256, 256, 0, stream>>>(ssbuf, msbuf);
        im2col<128, H, W><<<npix / 16, 256, 0, stream>>>(poolbuf, valbuf);
        kan_gemm<1152, OUT, H * W, 2, 4><<<dim3(npix / 64, 2, 4), 256, 0, stream>>>(
            valbuf, msbuf, ln_w3, ln_b3, wt3, convbuf);   // 4 x 8.4 MB partials
        bn_stats<<<dim3(8, OUT), 256, 0, stream>>>(convbuf, bb3, OUT, H * W, B, 4, stats3);
        long tot = (long)B * OUT * (H / 2) * (W / 2);  // 524288 == out_size
        bn_relu_pool<<<(tot + 255) / 256, 256, 0, stream>>>(
            convbuf, stats3, bb3, g3, be3, (float*)d_out, B, OUT, H, W, 4);
    }
}

// Round 15
// 459.157 us; speedup vs baseline: 1.0275x; 1.0275x over previous
//
#include <hip/hip_runtime.h>

typedef _Float16 half_t;
typedef __attribute__((ext_vector_type(8))) _Float16 half8;
typedef __attribute__((ext_vector_type(4))) float floatx4;

// ---------------------------------------------------------------------------
// Round 19: gemm/weights/split-K/bn = R15 exact (best, 465.6us; R18's
// LN-in-gemm regressed the gemm and is reverted). Single change: ln_prep
// rewritten two-phase to fix store-issue boundedness (R12 evidence: 65.5us,
// 37.7M scalar 2B stores = ~61us of pure store issue at 1/cy/CU; VALU diets
// never touched this). Phase 1: per-pixel mean/istd (wave-reduce) -> LDS.
// Phase 2: threads remap to (pixel, 8-elem chunk); half8 16B stores for
// pn AND sp (8x fewer store instructions), float4 lnw/lnb loads, LDS offs
// table for the gather. Stores coalesce: consecutive threads -> consecutive
// 16B. Math identical (same clamp, same exp forms) -> absmax unchanged.
// ---------------------------------------------------------------------------

#define RBF_SCALE 2.1019644f       // 1.75 * sqrt(log2 e)
#define RBF_G0   -4.2039288f       // RBF_SCALE * (-2)
#define RBF_2D    2.40224482f      // 2*sqrt(log2 e)
#define RBF_D2    1.44269504f      // log2 e
#define RBF_Q     0.13533528f      // e^-2
#define LOG2E     1.44269504f

// ---- patch gather + LayerNorm -> pn' (fp16), silu; 16 pixels/block ----
// block: 16 consecutive-in-x pixels (same row; W%16==0).
// phase 1: wave wv reduces pixels wv*4..wv*4+3 -> pms[16]
// phase 2: thread c -> (pixel p = c/CH, chunk q = c%CH), half8 stores.
template<int C, int H, int W>
__global__ __launch_bounds__(256)
void ln_prep(const float* __restrict__ x,
             const float* __restrict__ lnw, const float* __restrict__ lnb,
             half_t* __restrict__ pn, half_t* __restrict__ sp)
{
    const int HW = H * W, IN = C * 9, CH = IN / 8;   // IN%8==0 always
    const int NL = (IN + 63) / 64;
    __shared__ float xw[C * 57];                 // [C][3][19], cols 0..17 used
    __shared__ short offs[C * 9];                // i -> ch*57 + dy*19 + dx
    __shared__ float2 pms[16];                   // per-pixel (mean, istd)

    const int wv = threadIdx.x >> 6, lane = threadIdx.x & 63;
    const int pix0 = blockIdx.x * 16;
    const int b = pix0 / HW, hw0 = pix0 % HW;
    const int h = hw0 / W, x0 = hw0 % W;         // pixels x0..x0+15, same row
    const float* xb = x + (long)b * C * HW;

    // ---- cooperative stage: cols x0-1 .. x0+16, rows h-1..h+1 ----
    for (int idx = threadIdx.x; idx < C * 54; idx += 256) {
        int ch = idx / 54, rem = idx - ch * 54;
        int dy = rem / 18, col = rem - dy * 18;
        int y = h + dy - 1, xx = x0 + col - 1;
        float v = 0.f;
        if (y >= 0 && y < H && xx >= 0 && xx < W)
            v = xb[(long)ch * HW + y * W + xx];
        xw[ch * 57 + dy * 19 + col] = v;
    }
    // ---- offs table (once per block) ----
    for (int i = threadIdx.x; i < IN; i += 256) {
        int ch = i / 9, r = i - ch * 9;
        int dy = r / 3, dx = r - dy * 3;
        offs[i] = (short)(ch * 57 + dy * 19 + dx);
    }
    __syncthreads();

    // ---- phase 1: per-pixel stats ----
    #pragma unroll
    for (int p = 0; p < 4; ++p) {
        const int px = wv * 4 + p;
        float s = 0.f, s2 = 0.f;
        #pragma unroll
        for (int t = 0; t < NL; ++t) {
            int i = t * 64 + lane;
            if (i < IN) {
                float v = xw[offs[i] + px];
                s += v; s2 += v * v;
            }
        }
        #pragma unroll
        for (int off = 32; off > 0; off >>= 1) {
            s  += __shfl_down(s,  off, 64);
            s2 += __shfl_down(s2, off, 64);
        }
        if (lane == 0) {
            float mean = s / IN;
            float istd = rsqrtf(s2 / IN - mean * mean + 1e-5f);
            pms[px] = make_float2(mean, istd);
        }
    }
    __syncthreads();

    // ---- phase 2: chunk-parallel, half8 (16B) stores ----
    const int TOT = 16 * CH;
    for (int c = threadIdx.x; c < TOT; c += 256) {
        int p = c / CH, q = c - p * CH;
        float2 msv = pms[p];
        const float mean = msv.x, istd = msv.y;
        const int i0 = q * 8;
        float4 w0 = *(const float4*)(lnw + i0);
        float4 w1 = *(const float4*)(lnw + i0 + 4);
        float4 b0 = *(const float4*)(lnb + i0);
        float4 b1 = *(const float4*)(lnb + i0 + 4);
        float lw[8] = {w0.x, w0.y, w0.z, w0.w, w1.x, w1.y, w1.z, w1.w};
        float lb[8] = {b0.x, b0.y, b0.z, b0.w, b1.x, b1.y, b1.z, b1.w};
        half8 a, s8;
        #pragma unroll
        for (int e = 0; e < 8; ++e) {
            float val = xw[offs[i0 + e] + p];
            float pnv = fmaf((val - mean) * istd, lw[e], lb[e]) * RBF_SCALE;
            pnv = fminf(12.f, fmaxf(-12.f, pnv));   // clamp for recurrence
            a[e] = (half_t)pnv;
            float ev = __builtin_amdgcn_exp2f(-val * LOG2E);
            s8[e] = (half_t)(val * __builtin_amdgcn_rcpf(1.f + ev));
        }
        const long base = (long)(pix0 + p) * IN + i0;
        *(half8*)&pn[base] = a;
        *(half8*)&sp[base] = s8;
    }
}

// ---- fp32 weights -> fp16 packed [step][OUT][64], XOR pre-swizzle ----
// step s -> iblk = s/9, j = s%9; packed col uu holds k-unit (uu>>3)^(o&7):
// i = iblk*64 + ((uu>>3)^(o&7))*8 + (uu&7); k = j*IN + i (j<8 Ws, j==8 Wb).
template<int IN, int OUT>
__global__ __launch_bounds__(256)
void conv_w(const float* __restrict__ Ws, const float* __restrict__ Wb,
            half_t* __restrict__ Wt)
{
    const int NIB = (IN + 63) / 64, NSTEP = NIB * 9;
    int idx = blockIdx.x * 256 + threadIdx.x;
    if (idx >= OUT * NSTEP * 64) return;
    int uu = idx & 63;
    int t = idx >> 6;
    int o = t % OUT;
    int s = t / OUT;
    int iblk = s / 9, j = s % 9;
    int ulin = (((uu >> 3) ^ (o & 7)) << 3) + (uu & 7);
    int i = iblk * 64 + ulin;
    float v = 0.f;
    if (i < IN)
        v = (j < 8) ? Ws[(long)o * IN * 8 + i * 8 + j] : Wb[(long)o * IN + i];
    Wt[idx] = (half_t)v;
}

// ---- fused A-gen + MFMA GEMM (R15: 2-barrier loop + prefetch, M=64) ----
// block: 64 pixels x (4*NB*16) outputs at yoff; wave wv: NB*16 outputs.
// B via global_load_lds (linear dest, pre-swizzled source). A swizzled writes.
// LDS XOR swizzle: 16B unit w at w ^ (row & 7), row stride 64 halfs.
template<int IN, int OUT, int HW, int NB, int SPLIT>
__global__ __launch_bounds__(256)
void kan_gemm(const half_t* __restrict__ pn, const half_t* __restrict__ sp,
              const half_t* __restrict__ Wt, float* __restrict__ out)
{
    const int NIB = (IN + 63) / 64;

    __shared__ half_t As[64 * 64];
    __shared__ half_t Bs[NB * 64 * 64];

    const int tid = threadIdx.x;
    const int row = tid >> 2, q = tid & 3;
    const int pix = blockIdx.x * 64 + row;
    const half_t* pnrow = pn + (long)pix * IN;
    const half_t* sprow = sp + (long)pix * IN;

    const int wv = tid >> 6, lane = tid & 63;
    const int lr = lane & 15, lq = lane >> 4;
    const int u0 = (2 * q) ^ (row & 7);         // swizzled 16B units (A stage)
    const int u1 = (2 * q + 1) ^ (row & 7);
    const int yoff = blockIdx.y * (4 * NB * 16);

    floatx4 acc[NB][4] = {};
    float r[16], u[16];
    half8 pf0, pf1;                              // global prefetch pair

    const int grpA = (blockIdx.z * NIB) / SPLIT;         // group-aligned split
    const int grpB = ((blockIdx.z + 1) * NIB) / SPLIT;
    const int s0 = grpA * 9, s1 = grpB * 9;

    int jg = 0, ibg = grpA;    // A-gen state: next step to generate

    // clamped-address global load (tail chunks: weights are zero there, and
    // clamped pn in [-12,12] keeps the recurrence finite)
    auto ldglob = [&](const half_t* base, int ib, half8& a, half8& b) {
        int i0 = ib * 64 + q * 16;
        const half_t* pp = base + ((i0 < IN) ? i0 : 0);
        a = *(const half8*)pp;
        b = *(const half8*)(pp + 8);
    };

    auto stageB = [&](int it) {
        const half_t* wsrc = Wt + (long)it * OUT * 64
                              + (long)(yoff + wv * NB * 16) * 64;
        #pragma unroll
        for (int c = 0; c < NB * 2; ++c) {
            __builtin_amdgcn_global_load_lds(
                (const __attribute__((address_space(1))) void*)(wsrc + c * 512 + lane * 8),
                (__attribute__((address_space(3))) void*)(&Bs[wv * NB * 1024 + c * 512]),
                16, 0, 0);
        }
    };

    auto genA = [&]() {
        if (jg < 8) {
            if (jg == 0) {
                // pf holds pn(ibg), prefetched at previous jg==8 (or prologue)
                #pragma unroll
                for (int kk = 0; kk < 8; ++kk) {
                    float d0 = (float)pf0[kk] - RBF_G0;
                    float d1 = (float)pf1[kk] - RBF_G0;
                    r[kk]     = __builtin_amdgcn_exp2f(-(d0 * d0));
                    u[kk]     = __builtin_amdgcn_exp2f(fmaf(RBF_2D, d0, -RBF_D2));
                    r[kk + 8] = __builtin_amdgcn_exp2f(-(d1 * d1));
                    u[kk + 8] = __builtin_amdgcn_exp2f(fmaf(RBF_2D, d1, -RBF_D2));
                }
            }
            half8 a0, a1;
            #pragma unroll
            for (int kk = 0; kk < 8; ++kk) {
                a0[kk] = (half_t)r[kk];
                a1[kk] = (half_t)r[kk + 8];
            }
            *(half8*)&As[row * 64 + u0 * 8] = a0;
            *(half8*)&As[row * 64 + u1 * 8] = a1;
            if (jg < 7) {
                #pragma unroll
                for (int kk = 0; kk < 16; ++kk) { r[kk] *= u[kk]; u[kk] *= RBF_Q; }
            }
            if (jg == 7) ldglob(sprow, ibg, pf0, pf1);      // prefetch silu
        } else {
            // pf holds sp(ibg), prefetched at jg==7
            *(half8*)&As[row * 64 + u0 * 8] = pf0;
            *(half8*)&As[row * 64 + u1 * 8] = pf1;
            ldglob(pnrow, ibg + 1, pf0, pf1);               // prefetch next pn
        }
        if (++jg == 9) { jg = 0; ++ibg; }
    };

    auto domfma = [&]() {
        __builtin_amdgcn_s_setprio(1);
        #pragma unroll
        for (int ks = 0; ks < 2; ++ks) {
            half8 af[4], bf[NB];
            #pragma unroll
            for (int mf = 0; mf < 4; ++mf) {
                int rr = mf * 16 + lr;
                af[mf] = *(const half8*)&As[rr * 64 + (((ks * 4 + lq) ^ (rr & 7)) * 8)];
            }
            #pragma unroll
            for (int nb = 0; nb < NB; ++nb) {
                int rr = wv * NB * 16 + nb * 16 + lr;
                bf[nb] = *(const half8*)&Bs[rr * 64 + (((ks * 4 + lq) ^ (rr & 7)) * 8)];
            }
            #pragma unroll
            for (int nb = 0; nb < NB; ++nb)
                #pragma unroll
                for (int mf = 0; mf < 4; ++mf)
                    acc[nb][mf] = __builtin_amdgcn_mfma_f32_16x16x32_f16(
                        bf[nb], af[mf], acc[nb][mf], 0, 0, 0);
        }
        __builtin_amdgcn_s_setprio(0);
    };

    // ---- prologue: prefetch pn(grpA) ----
    ldglob(pnrow, grpA, pf0, pf1);

    // ---- main loop: stage (async) + A-gen, barrier, MFMA ----
    for (int it = s0; it < s1; ++it) {
        __syncthreads();           // previous MFMA reads done
        stageB(it);                // async gload_lds -> Bs
        genA();                    // VALU + swizzled ds_write -> As
        __syncthreads();           // drain: As/Bs ready
        domfma();
    }

    // ---- epilogue: plain stores into z-partial slab ----
    const long zoff = (long)blockIdx.z * ((long)gridDim.x * 64) * OUT;
    #pragma unroll
    for (int nb = 0; nb < NB; ++nb)
    #pragma unroll
    for (int mf = 0; mf < 4; ++mf)
    #pragma unroll
    for (int reg = 0; reg < 4; ++reg) {
        int o  = yoff + wv * NB * 16 + nb * 16 + lq * 4 + reg;
        int p2 = blockIdx.x * 64 + mf * 16 + lr;
        int b2 = p2 / HW, hw2 = p2 % HW;
        out[zoff + ((long)b2 * OUT + o) * HW + hw2] = acc[nb][mf][reg];
    }
}

// ---- BatchNorm batch-stats over summed z-partials (bias folded in) ----
__launch_bounds__(256)
__global__ void bn_stats(const float* __restrict__ h, const float* __restrict__ bias,
                         int C, int HW, int B, int nz, float* __restrict__ sums)
{
    int c = blockIdx.y;
    float bbc = bias[c];
    long zstride = (long)B * C * HW;
    int total = B * HW;
    float s = 0.f, s2 = 0.f;
    for (int idx = blockIdx.x * 256 + threadIdx.x; idx < total; idx += 256 * gridDim.x) {
        int b = idx / HW, r = idx % HW;
        long base = ((long)b * C + c) * HW + r;
        float v = bbc;
        for (int z = 0; z < nz; ++z) v += h[z * zstride + base];
        s += v; s2 += v * v;
    }
    for (int off = 32; off > 0; off >>= 1) {
        s  += __shfl_down(s,  off, 64);
        s2 += __shfl_down(s2, off, 64);
    }
    __shared__ float rs[4], rs2[4];
    int lane = threadIdx.x & 63, wid = threadIdx.x >> 6;
    if (lane == 0) { rs[wid] = s; rs2[wid] = s2; }
    __syncthreads();
    if (threadIdx.x == 0) {
        atomicAdd(&sums[c],     rs[0] + rs[1] + rs[2] + rs[3]);
        atomicAdd(&sums[C + c], rs2[0] + rs2[1] + rs2[2] + rs2[3]);
    }
}

__launch_bounds__(256)
__global__ void bn_relu_pool(const float* __restrict__ h, const float* __restrict__ sums,
                             const float* __restrict__ bias,
                             const float* __restrict__ gamma, const float* __restrict__ beta,
                             float* __restrict__ out, int B, int C, int H, int W, int nz)
{
    int Ho = H / 2, Wo = W / 2;
    long total = (long)B * C * Ho * Wo;
    long idx = (long)blockIdx.x * 256 + threadIdx.x;
    if (idx >= total) return;
    int pw = idx % Wo; long t = idx / Wo;
    int ph = t % Ho; t /= Ho;
    int c = t % C; int b = (int)(t / C);

    float M = (float)B * H * W;
    float mean = sums[c] / M;
    float var  = sums[C + c] / M - mean * mean;
    float scale = gamma[c] * rsqrtf(var + 1e-5f);
    float shift = beta[c] - mean * scale + bias[c] * scale;  // fold conv bias

    long zstride = (long)B * C * H * W;
    const float* hp = h + ((long)b * C + c) * H * W;
    float m = 0.f;  // post-relu >= 0
    #pragma unroll
    for (int i = 0; i < 2; ++i)
        #pragma unroll
        for (int j = 0; j < 2; ++j) {
            long off = (2 * ph + i) * W + 2 * pw + j;
            float v = 0.f;
            for (int z = 0; z < nz; ++z) v += hp[z * zstride + off];
            v = v * scale + shift;
            m = fmaxf(m, v);
        }
    out[idx] = m;
}

extern "C" void kernel_launch(void* const* d_in, const int* in_sizes, int n_in,
                              void* d_out, int out_size, void* d_ws, size_t ws_size,
                              hipStream_t stream) {
    const float* x     = (const float*)d_in[0];
    const float* ln_w1 = (const float*)d_in[1];  const float* ln_b1 = (const float*)d_in[2];
    const float* Wb1   = (const float*)d_in[3];  const float* bb1   = (const float*)d_in[4];
    const float* Ws1   = (const float*)d_in[5];  const float* g1    = (const float*)d_in[6];
    const float* be1   = (const float*)d_in[7];
    const float* ln_w2 = (const float*)d_in[8];  const float* ln_b2 = (const float*)d_in[9];
    const float* Wb2   = (const float*)d_in[10]; const float* bb2   = (const float*)d_in[11];
    const float* Ws2   = (const float*)d_in[12]; const float* g2    = (const float*)d_in[13];
    const float* be2   = (const float*)d_in[14];
    const float* ln_w3 = (const float*)d_in[15]; const float* ln_b3 = (const float*)d_in[16];
    const float* Wb3   = (const float*)d_in[17]; const float* bb3   = (const float*)d_in[18];
    const float* Ws3   = (const float*)d_in[19]; const float* g3    = (const float*)d_in[20];
    const float* be3   = (const float*)d_in[21];

    const int B = 32;
    char* ws = (char*)d_ws;
    float*  convbuf = (float*)(ws + 0);              // 33,554,432 (z-partials L2/L3)
    float*  poolbuf = (float*)(ws + 33554432);       //  8,388,608
    float*  stats1  = (float*)(ws + 41943040);       //  2048 x3
    float*  stats2  = (float*)(ws + 41945088);
    float*  stats3  = (float*)(ws + 41947136);
    half_t* wt1     = (half_t*)(ws + 41949184);      //   221,184  (27 x 64 x 64)
    half_t* wt2     = (half_t*)(ws + 42170368);      // 1,327,104  (81 x 128 x 64)
    half_t* wt3     = (half_t*)(ws + 43497472);      // 5,308,416  (162 x 256 x 64)
    half_t* pnbuf   = (half_t*)(ws + 48805888);      // 37,748,736 (max 131072x144)
    half_t* spbuf   = (half_t*)(ws + 86554624);      // 37,748,736
    // total: 124,303,360 B

    hipMemsetAsync(stats1, 0, 6144, stream);

    conv_w<144, 64><<<(64 * 27 * 64 + 255) / 256, 256, 0, stream>>>(Ws1, Wb1, wt1);
    conv_w<576, 128><<<(128 * 81 * 64 + 255) / 256, 256, 0, stream>>>(Ws2, Wb2, wt2);
    conv_w<1152, 256><<<(256 * 162 * 64 + 255) / 256, 256, 0, stream>>>(Ws3, Wb3, wt3);

    // ---------------- layer 1: C=16, H=W=64, OUT=64, NB=1, y=1, z=1 ---------
    {
        const int H = 64, W = 64, OUT = 64;
        int npix = B * H * W;                    // 131072
        ln_prep<16, H, W><<<npix / 16, 256, 0, stream>>>(x, ln_w1, ln_b1, pnbuf, spbuf);
        kan_gemm<144, OUT, H * W, 1, 1><<<dim3(npix / 64, 1, 1), 256, 0, stream>>>(
            pnbuf, spbuf, wt1, convbuf);
        bn_stats<<<dim3(64, OUT), 256, 0, stream>>>(convbuf, bb1, OUT, H * W, B, 1, stats1);
        long tot = (long)B * OUT * (H / 2) * (W / 2);
        bn_relu_pool<<<(tot + 255) / 256, 256, 0, stream>>>(
            convbuf, stats1, bb1, g1, be1, poolbuf, B, OUT, H, W, 1);
    }
    // ---------------- layer 2: C=64, H=W=32, OUT=128, NB=2, y=1, z=2 --------
    {
        const int H = 32, W = 32, OUT = 128;
        int npix = B * H * W;                    // 32768
        ln_prep<64, H, W><<<npix / 16, 256, 0, stream>>>(poolbuf, ln_w2, ln_b2, pnbuf, spbuf);
        kan_gemm<576, OUT, H * W, 2, 2><<<dim3(npix / 64, 1, 2), 256, 0, stream>>>(
            pnbuf, spbuf, wt2, convbuf);           // 2 x 16.8 MB partials in convbuf
        bn_stats<<<dim3(16, OUT), 256, 0, stream>>>(convbuf, bb2, OUT, H * W, B, 2, stats2);
        long tot = (long)B * OUT * (H / 2) * (W / 2);
        bn_relu_pool<<<(tot + 255) / 256, 256, 0, stream>>>(
            convbuf, stats2, bb2, g2, be2, poolbuf, B, OUT, H, W, 2);
    }
    // ---------------- layer 3: C=128, H=W=16, OUT=256, NB=2, y=2, z=4 -------
    {
        const int H = 16, W = 16, OUT = 256;
        int npix = B * H * W;                    // 8192
        ln_prep<128, H, W><<<npix / 16, 256, 0, stream>>>(poolbuf, ln_w3, ln_b3, pnbuf, spbuf);
        kan_gemm<1152, OUT, H * W, 2, 4><<<dim3(npix / 64, 2, 4), 256, 0, stream>>>(
            pnbuf, spbuf, wt3, convbuf);           // 4 x 8.4 MB partials in convbuf
        bn_stats<<<dim3(8, OUT), 256, 0, stream>>>(convbuf, bb3, OUT, H * W, B, 4, stats3);
        long tot = (long)B * OUT * (H / 2) * (W / 2);  // 524288 == out_size
        bn_relu_pool<<<(tot + 255) / 256, 256, 0, stream>>>(
            convbuf, stats3, bb3, g3, be3, (float*)d_out, B, OUT, H, W, 4);
    }
}

// Round 16
// 453.182 us; speedup vs baseline: 1.0411x; 1.0132x over previous
//
#include <hip/hip_runtime.h>

typedef _Float16 half_t;
typedef __attribute__((ext_vector_type(8))) _Float16 half8;
typedef __attribute__((ext_vector_type(4))) float floatx4;

// ---------------------------------------------------------------------------
// Round 20: R19 (best, 459.2us) + vectorized BN tail (gemm/ln_prep/weights
// untouched as control):
//  - bn_stats: float4 loads, 4 pixels/thread grid-stride.
//  - bn_relu_pool: 4 outputs/thread; per z-slab 4x float4 row loads for the
//    2x2 windows of 4 consecutive pw; z-sum in float4; per-element
//    scale/shift then relu-max (identical math order); float4 store.
// Six bn dispatches were ~35-45us by traffic arithmetic (scalar loads,
// strided pool gather); 4x fewer mem instructions each.
// ---------------------------------------------------------------------------

#define RBF_SCALE 2.1019644f       // 1.75 * sqrt(log2 e)
#define RBF_G0   -4.2039288f       // RBF_SCALE * (-2)
#define RBF_2D    2.40224482f      // 2*sqrt(log2 e)
#define RBF_D2    1.44269504f      // log2 e
#define RBF_Q     0.13533528f      // e^-2
#define LOG2E     1.44269504f

// ---- patch gather + LayerNorm -> pn' (fp16), silu; 16 pixels/block ----
// block: 16 consecutive-in-x pixels (same row; W%16==0).
// phase 1: wave wv reduces pixels wv*4..wv*4+3 -> pms[16]
// phase 2: thread c -> (pixel p = c/CH, chunk q = c%CH), half8 stores.
template<int C, int H, int W>
__global__ __launch_bounds__(256)
void ln_prep(const float* __restrict__ x,
             const float* __restrict__ lnw, const float* __restrict__ lnb,
             half_t* __restrict__ pn, half_t* __restrict__ sp)
{
    const int HW = H * W, IN = C * 9, CH = IN / 8;   // IN%8==0 always
    const int NL = (IN + 63) / 64;
    __shared__ float xw[C * 57];                 // [C][3][19], cols 0..17 used
    __shared__ short offs[C * 9];                // i -> ch*57 + dy*19 + dx
    __shared__ float2 pms[16];                   // per-pixel (mean, istd)

    const int wv = threadIdx.x >> 6, lane = threadIdx.x & 63;
    const int pix0 = blockIdx.x * 16;
    const int b = pix0 / HW, hw0 = pix0 % HW;
    const int h = hw0 / W, x0 = hw0 % W;         // pixels x0..x0+15, same row
    const float* xb = x + (long)b * C * HW;

    // ---- cooperative stage: cols x0-1 .. x0+16, rows h-1..h+1 ----
    for (int idx = threadIdx.x; idx < C * 54; idx += 256) {
        int ch = idx / 54, rem = idx - ch * 54;
        int dy = rem / 18, col = rem - dy * 18;
        int y = h + dy - 1, xx = x0 + col - 1;
        float v = 0.f;
        if (y >= 0 && y < H && xx >= 0 && xx < W)
            v = xb[(long)ch * HW + y * W + xx];
        xw[ch * 57 + dy * 19 + col] = v;
    }
    // ---- offs table (once per block) ----
    for (int i = threadIdx.x; i < IN; i += 256) {
        int ch = i / 9, r = i - ch * 9;
        int dy = r / 3, dx = r - dy * 3;
        offs[i] = (short)(ch * 57 + dy * 19 + dx);
    }
    __syncthreads();

    // ---- phase 1: per-pixel stats ----
    #pragma unroll
    for (int p = 0; p < 4; ++p) {
        const int px = wv * 4 + p;
        float s = 0.f, s2 = 0.f;
        #pragma unroll
        for (int t = 0; t < NL; ++t) {
            int i = t * 64 + lane;
            if (i < IN) {
                float v = xw[offs[i] + px];
                s += v; s2 += v * v;
            }
        }
        #pragma unroll
        for (int off = 32; off > 0; off >>= 1) {
            s  += __shfl_down(s,  off, 64);
            s2 += __shfl_down(s2, off, 64);
        }
        if (lane == 0) {
            float mean = s / IN;
            float istd = rsqrtf(s2 / IN - mean * mean + 1e-5f);
            pms[px] = make_float2(mean, istd);
        }
    }
    __syncthreads();

    // ---- phase 2: chunk-parallel, half8 (16B) stores ----
    const int TOT = 16 * CH;
    for (int c = threadIdx.x; c < TOT; c += 256) {
        int p = c / CH, q = c - p * CH;
        float2 msv = pms[p];
        const float mean = msv.x, istd = msv.y;
        const int i0 = q * 8;
        float4 w0 = *(const float4*)(lnw + i0);
        float4 w1 = *(const float4*)(lnw + i0 + 4);
        float4 b0 = *(const float4*)(lnb + i0);
        float4 b1 = *(const float4*)(lnb + i0 + 4);
        float lw[8] = {w0.x, w0.y, w0.z, w0.w, w1.x, w1.y, w1.z, w1.w};
        float lb[8] = {b0.x, b0.y, b0.z, b0.w, b1.x, b1.y, b1.z, b1.w};
        half8 a, s8;
        #pragma unroll
        for (int e = 0; e < 8; ++e) {
            float val = xw[offs[i0 + e] + p];
            float pnv = fmaf((val - mean) * istd, lw[e], lb[e]) * RBF_SCALE;
            pnv = fminf(12.f, fmaxf(-12.f, pnv));   // clamp for recurrence
            a[e] = (half_t)pnv;
            float ev = __builtin_amdgcn_exp2f(-val * LOG2E);
            s8[e] = (half_t)(val * __builtin_amdgcn_rcpf(1.f + ev));
        }
        const long base = (long)(pix0 + p) * IN + i0;
        *(half8*)&pn[base] = a;
        *(half8*)&sp[base] = s8;
    }
}

// ---- fp32 weights -> fp16 packed [step][OUT][64], XOR pre-swizzle ----
// step s -> iblk = s/9, j = s%9; packed col uu holds k-unit (uu>>3)^(o&7):
// i = iblk*64 + ((uu>>3)^(o&7))*8 + (uu&7); k = j*IN + i (j<8 Ws, j==8 Wb).
template<int IN, int OUT>
__global__ __launch_bounds__(256)
void conv_w(const float* __restrict__ Ws, const float* __restrict__ Wb,
            half_t* __restrict__ Wt)
{
    const int NIB = (IN + 63) / 64, NSTEP = NIB * 9;
    int idx = blockIdx.x * 256 + threadIdx.x;
    if (idx >= OUT * NSTEP * 64) return;
    int uu = idx & 63;
    int t = idx >> 6;
    int o = t % OUT;
    int s = t / OUT;
    int iblk = s / 9, j = s % 9;
    int ulin = (((uu >> 3) ^ (o & 7)) << 3) + (uu & 7);
    int i = iblk * 64 + ulin;
    float v = 0.f;
    if (i < IN)
        v = (j < 8) ? Ws[(long)o * IN * 8 + i * 8 + j] : Wb[(long)o * IN + i];
    Wt[idx] = (half_t)v;
}

// ---- fused A-gen + MFMA GEMM (R15: 2-barrier loop + prefetch, M=64) ----
// block: 64 pixels x (4*NB*16) outputs at yoff; wave wv: NB*16 outputs.
// B via global_load_lds (linear dest, pre-swizzled source). A swizzled writes.
// LDS XOR swizzle: 16B unit w at w ^ (row & 7), row stride 64 halfs.
template<int IN, int OUT, int HW, int NB, int SPLIT>
__global__ __launch_bounds__(256)
void kan_gemm(const half_t* __restrict__ pn, const half_t* __restrict__ sp,
              const half_t* __restrict__ Wt, float* __restrict__ out)
{
    const int NIB = (IN + 63) / 64;

    __shared__ half_t As[64 * 64];
    __shared__ half_t Bs[NB * 64 * 64];

    const int tid = threadIdx.x;
    const int row = tid >> 2, q = tid & 3;
    const int pix = blockIdx.x * 64 + row;
    const half_t* pnrow = pn + (long)pix * IN;
    const half_t* sprow = sp + (long)pix * IN;

    const int wv = tid >> 6, lane = tid & 63;
    const int lr = lane & 15, lq = lane >> 4;
    const int u0 = (2 * q) ^ (row & 7);         // swizzled 16B units (A stage)
    const int u1 = (2 * q + 1) ^ (row & 7);
    const int yoff = blockIdx.y * (4 * NB * 16);

    floatx4 acc[NB][4] = {};
    float r[16], u[16];
    half8 pf0, pf1;                              // global prefetch pair

    const int grpA = (blockIdx.z * NIB) / SPLIT;         // group-aligned split
    const int grpB = ((blockIdx.z + 1) * NIB) / SPLIT;
    const int s0 = grpA * 9, s1 = grpB * 9;

    int jg = 0, ibg = grpA;    // A-gen state: next step to generate

    // clamped-address global load (tail chunks: weights are zero there, and
    // clamped pn in [-12,12] keeps the recurrence finite)
    auto ldglob = [&](const half_t* base, int ib, half8& a, half8& b) {
        int i0 = ib * 64 + q * 16;
        const half_t* pp = base + ((i0 < IN) ? i0 : 0);
        a = *(const half8*)pp;
        b = *(const half8*)(pp + 8);
    };

    auto stageB = [&](int it) {
        const half_t* wsrc = Wt + (long)it * OUT * 64
                              + (long)(yoff + wv * NB * 16) * 64;
        #pragma unroll
        for (int c = 0; c < NB * 2; ++c) {
            __builtin_amdgcn_global_load_lds(
                (const __attribute__((address_space(1))) void*)(wsrc + c * 512 + lane * 8),
                (__attribute__((address_space(3))) void*)(&Bs[wv * NB * 1024 + c * 512]),
                16, 0, 0);
        }
    };

    auto genA = [&]() {
        if (jg < 8) {
            if (jg == 0) {
                // pf holds pn(ibg), prefetched at previous jg==8 (or prologue)
                #pragma unroll
                for (int kk = 0; kk < 8; ++kk) {
                    float d0 = (float)pf0[kk] - RBF_G0;
                    float d1 = (float)pf1[kk] - RBF_G0;
                    r[kk]     = __builtin_amdgcn_exp2f(-(d0 * d0));
                    u[kk]     = __builtin_amdgcn_exp2f(fmaf(RBF_2D, d0, -RBF_D2));
                    r[kk + 8] = __builtin_amdgcn_exp2f(-(d1 * d1));
                    u[kk + 8] = __builtin_amdgcn_exp2f(fmaf(RBF_2D, d1, -RBF_D2));
                }
            }
            half8 a0, a1;
            #pragma unroll
            for (int kk = 0; kk < 8; ++kk) {
                a0[kk] = (half_t)r[kk];
                a1[kk] = (half_t)r[kk + 8];
            }
            *(half8*)&As[row * 64 + u0 * 8] = a0;
            *(half8*)&As[row * 64 + u1 * 8] = a1;
            if (jg < 7) {
                #pragma unroll
                for (int kk = 0; kk < 16; ++kk) { r[kk] *= u[kk]; u[kk] *= RBF_Q; }
            }
            if (jg == 7) ldglob(sprow, ibg, pf0, pf1);      // prefetch silu
        } else {
            // pf holds sp(ibg), prefetched at jg==7
            *(half8*)&As[row * 64 + u0 * 8] = pf0;
            *(half8*)&As[row * 64 + u1 * 8] = pf1;
            ldglob(pnrow, ibg + 1, pf0, pf1);               // prefetch next pn
        }
        if (++jg == 9) { jg = 0; ++ibg; }
    };

    auto domfma = [&]() {
        __builtin_amdgcn_s_setprio(1);
        #pragma unroll
        for (int ks = 0; ks < 2; ++ks) {
            half8 af[4], bf[NB];
            #pragma unroll
            for (int mf = 0; mf < 4; ++mf) {
                int rr = mf * 16 + lr;
                af[mf] = *(const half8*)&As[rr * 64 + (((ks * 4 + lq) ^ (rr & 7)) * 8)];
            }
            #pragma unroll
            for (int nb = 0; nb < NB; ++nb) {
                int rr = wv * NB * 16 + nb * 16 + lr;
                bf[nb] = *(const half8*)&Bs[rr * 64 + (((ks * 4 + lq) ^ (rr & 7)) * 8)];
            }
            #pragma unroll
            for (int nb = 0; nb < NB; ++nb)
                #pragma unroll
                for (int mf = 0; mf < 4; ++mf)
                    acc[nb][mf] = __builtin_amdgcn_mfma_f32_16x16x32_f16(
                        bf[nb], af[mf], acc[nb][mf], 0, 0, 0);
        }
        __builtin_amdgcn_s_setprio(0);
    };

    // ---- prologue: prefetch pn(grpA) ----
    ldglob(pnrow, grpA, pf0, pf1);

    // ---- main loop: stage (async) + A-gen, barrier, MFMA ----
    for (int it = s0; it < s1; ++it) {
        __syncthreads();           // previous MFMA reads done
        stageB(it);                // async gload_lds -> Bs
        genA();                    // VALU + swizzled ds_write -> As
        __syncthreads();           // drain: As/Bs ready
        domfma();
    }

    // ---- epilogue: plain stores into z-partial slab ----
    const long zoff = (long)blockIdx.z * ((long)gridDim.x * 64) * OUT;
    #pragma unroll
    for (int nb = 0; nb < NB; ++nb)
    #pragma unroll
    for (int mf = 0; mf < 4; ++mf)
    #pragma unroll
    for (int reg = 0; reg < 4; ++reg) {
        int o  = yoff + wv * NB * 16 + nb * 16 + lq * 4 + reg;
        int p2 = blockIdx.x * 64 + mf * 16 + lr;
        int b2 = p2 / HW, hw2 = p2 % HW;
        out[zoff + ((long)b2 * OUT + o) * HW + hw2] = acc[nb][mf][reg];
    }
}

// ---- BatchNorm batch-stats over summed z-partials, float4 loads ----
__launch_bounds__(256)
__global__ void bn_stats(const float* __restrict__ h, const float* __restrict__ bias,
                         int C, int HW, int B, int nz, float* __restrict__ sums)
{
    int c = blockIdx.y;
    float bbc = bias[c];
    long zstride = (long)B * C * HW;
    int hw4 = HW / 4;                            // HW % 4 == 0 always
    int total4 = B * hw4;
    float s = 0.f, s2 = 0.f;
    for (int idx = blockIdx.x * 256 + threadIdx.x; idx < total4; idx += 256 * gridDim.x) {
        int b = idx / hw4, r4 = idx - b * hw4;
        long base = ((long)b * C + c) * HW + (long)r4 * 4;
        float4 a = make_float4(bbc, bbc, bbc, bbc);
        for (int z = 0; z < nz; ++z) {
            float4 p = *(const float4*)&h[z * zstride + base];
            a.x += p.x; a.y += p.y; a.z += p.z; a.w += p.w;
        }
        s  += a.x + a.y + a.z + a.w;
        s2 += a.x * a.x + a.y * a.y + a.z * a.z + a.w * a.w;
    }
    for (int off = 32; off > 0; off >>= 1) {
        s  += __shfl_down(s,  off, 64);
        s2 += __shfl_down(s2, off, 64);
    }
    __shared__ float rs[4], rs2[4];
    int lane = threadIdx.x & 63, wid = threadIdx.x >> 6;
    if (lane == 0) { rs[wid] = s; rs2[wid] = s2; }
    __syncthreads();
    if (threadIdx.x == 0) {
        atomicAdd(&sums[c],     rs[0] + rs[1] + rs[2] + rs[3]);
        atomicAdd(&sums[C + c], rs2[0] + rs2[1] + rs2[2] + rs2[3]);
    }
}

// ---- BN normalize + ReLU + 2x2 maxpool, 4 outputs/thread (float4) ----
__launch_bounds__(256)
__global__ void bn_relu_pool(const float* __restrict__ h, const float* __restrict__ sums,
                             const float* __restrict__ bias,
                             const float* __restrict__ gamma, const float* __restrict__ beta,
                             float* __restrict__ out, int B, int C, int H, int W, int nz)
{
    int Ho = H / 2, Wo = W / 2, Wo4 = Wo / 4;    // Wo % 4 == 0 always
    long total4 = (long)B * C * Ho * Wo4;
    long idx = (long)blockIdx.x * 256 + threadIdx.x;
    if (idx >= total4) return;
    int pw4 = idx % Wo4; long t = idx / Wo4;
    int ph = t % Ho; t /= Ho;
    int c = t % C; int b = (int)(t / C);
    int pw0 = pw4 * 4;

    float M = (float)B * H * W;
    float mean = sums[c] / M;
    float var  = sums[C + c] / M - mean * mean;
    float scale = gamma[c] * rsqrtf(var + 1e-5f);
    float shift = beta[c] - mean * scale + bias[c] * scale;  // fold conv bias

    long zstride = (long)B * C * H * W;
    const float* hp = h + ((long)b * C + c) * H * W;
    long off0 = (long)(2 * ph) * W + 2 * pw0;    // row 2ph, cols 2pw0..2pw0+7
    long off1 = off0 + W;

    float4 r0a = make_float4(0.f, 0.f, 0.f, 0.f), r0b = r0a, r1a = r0a, r1b = r0a;
    for (int z = 0; z < nz; ++z) {
        const float* hz = hp + z * zstride;
        float4 p;
        p = *(const float4*)&hz[off0];     r0a.x += p.x; r0a.y += p.y; r0a.z += p.z; r0a.w += p.w;
        p = *(const float4*)&hz[off0 + 4]; r0b.x += p.x; r0b.y += p.y; r0b.z += p.z; r0b.w += p.w;
        p = *(const float4*)&hz[off1];     r1a.x += p.x; r1a.y += p.y; r1a.z += p.z; r1a.w += p.w;
        p = *(const float4*)&hz[off1 + 4]; r1b.x += p.x; r1b.y += p.y; r1b.z += p.z; r1b.w += p.w;
    }

    // per-element normalize then relu-max over each 2x2 window
    float e[8];  // row0 cols 0..7 normalized
    e[0]=fmaf(r0a.x,scale,shift); e[1]=fmaf(r0a.y,scale,shift);
    e[2]=fmaf(r0a.z,scale,shift); e[3]=fmaf(r0a.w,scale,shift);
    e[4]=fmaf(r0b.x,scale,shift); e[5]=fmaf(r0b.y,scale,shift);
    e[6]=fmaf(r0b.z,scale,shift); e[7]=fmaf(r0b.w,scale,shift);
    float f[8];  // row1
    f[0]=fmaf(r1a.x,scale,shift); f[1]=fmaf(r1a.y,scale,shift);
    f[2]=fmaf(r1a.z,scale,shift); f[3]=fmaf(r1a.w,scale,shift);
    f[4]=fmaf(r1b.x,scale,shift); f[5]=fmaf(r1b.y,scale,shift);
    f[6]=fmaf(r1b.z,scale,shift); f[7]=fmaf(r1b.w,scale,shift);

    float4 o4;
    o4.x = fmaxf(0.f, fmaxf(fmaxf(e[0], e[1]), fmaxf(f[0], f[1])));
    o4.y = fmaxf(0.f, fmaxf(fmaxf(e[2], e[3]), fmaxf(f[2], f[3])));
    o4.z = fmaxf(0.f, fmaxf(fmaxf(e[4], e[5]), fmaxf(f[4], f[5])));
    o4.w = fmaxf(0.f, fmaxf(fmaxf(e[6], e[7]), fmaxf(f[6], f[7])));

    long obase = (((long)b * C + c) * Ho + ph) * Wo + pw0;
    *(float4*)&out[obase] = o4;
}

extern "C" void kernel_launch(void* const* d_in, const int* in_sizes, int n_in,
                              void* d_out, int out_size, void* d_ws, size_t ws_size,
                              hipStream_t stream) {
    const float* x     = (const float*)d_in[0];
    const float* ln_w1 = (const float*)d_in[1];  const float* ln_b1 = (const float*)d_in[2];
    const float* Wb1   = (const float*)d_in[3];  const float* bb1   = (const float*)d_in[4];
    const float* Ws1   = (const float*)d_in[5];  const float* g1    = (const float*)d_in[6];
    const float* be1   = (const float*)d_in[7];
    const float* ln_w2 = (const float*)d_in[8];  const float* ln_b2 = (const float*)d_in[9];
    const float* Wb2   = (const float*)d_in[10]; const float* bb2   = (const float*)d_in[11];
    const float* Ws2   = (const float*)d_in[12]; const float* g2    = (const float*)d_in[13];
    const float* be2   = (const float*)d_in[14];
    const float* ln_w3 = (const float*)d_in[15]; const float* ln_b3 = (const float*)d_in[16];
    const float* Wb3   = (const float*)d_in[17]; const float* bb3   = (const float*)d_in[18];
    const float* Ws3   = (const float*)d_in[19]; const float* g3    = (const float*)d_in[20];
    const float* be3   = (const float*)d_in[21];

    const int B = 32;
    char* ws = (char*)d_ws;
    float*  convbuf = (float*)(ws + 0);              // 33,554,432 (z-partials L2/L3)
    float*  poolbuf = (float*)(ws + 33554432);       //  8,388,608
    float*  stats1  = (float*)(ws + 41943040);       //  2048 x3
    float*  stats2  = (float*)(ws + 41945088);
    float*  stats3  = (float*)(ws + 41947136);
    half_t* wt1     = (half_t*)(ws + 41949184);      //   221,184  (27 x 64 x 64)
    half_t* wt2     = (half_t*)(ws + 42170368);      // 1,327,104  (81 x 128 x 64)
    half_t* wt3     = (half_t*)(ws + 43497472);      // 5,308,416  (162 x 256 x 64)
    half_t* pnbuf   = (half_t*)(ws + 48805888);      // 37,748,736 (max 131072x144)
    half_t* spbuf   = (half_t*)(ws + 86554624);      // 37,748,736
    // total: 124,303,360 B

    hipMemsetAsync(stats1, 0, 6144, stream);

    conv_w<144, 64><<<(64 * 27 * 64 + 255) / 256, 256, 0, stream>>>(Ws1, Wb1, wt1);
    conv_w<576, 128><<<(128 * 81 * 64 + 255) / 256, 256, 0, stream>>>(Ws2, Wb2, wt2);
    conv_w<1152, 256><<<(256 * 162 * 64 + 255) / 256, 256, 0, stream>>>(Ws3, Wb3, wt3);

    // ---------------- layer 1: C=16, H=W=64, OUT=64, NB=1, y=1, z=1 ---------
    {
        const int H = 64, W = 64, OUT = 64;
        int npix = B * H * W;                    // 131072
        ln_prep<16, H, W><<<npix / 16, 256, 0, stream>>>(x, ln_w1, ln_b1, pnbuf, spbuf);
        kan_gemm<144, OUT, H * W, 1, 1><<<dim3(npix / 64, 1, 1), 256, 0, stream>>>(
            pnbuf, spbuf, wt1, convbuf);
        bn_stats<<<dim3(64, OUT), 256, 0, stream>>>(convbuf, bb1, OUT, H * W, B, 1, stats1);
        long tot4 = (long)B * OUT * (H / 2) * (W / 2) / 4;
        bn_relu_pool<<<(tot4 + 255) / 256, 256, 0, stream>>>(
            convbuf, stats1, bb1, g1, be1, poolbuf, B, OUT, H, W, 1);
    }
    // ---------------- layer 2: C=64, H=W=32, OUT=128, NB=2, y=1, z=2 --------
    {
        const int H = 32, W = 32, OUT = 128;
        int npix = B * H * W;                    // 32768
        ln_prep<64, H, W><<<npix / 16, 256, 0, stream>>>(poolbuf, ln_w2, ln_b2, pnbuf, spbuf);
        kan_gemm<576, OUT, H * W, 2, 2><<<dim3(npix / 64, 1, 2), 256, 0, stream>>>(
            pnbuf, spbuf, wt2, convbuf);           // 2 x 16.8 MB partials in convbuf
        bn_stats<<<dim3(16, OUT), 256, 0, stream>>>(convbuf, bb2, OUT, H * W, B, 2, stats2);
        long tot4 = (long)B * OUT * (H / 2) * (W / 2) / 4;
        bn_relu_pool<<<(tot4 + 255) / 256, 256, 0, stream>>>(
            convbuf, stats2, bb2, g2, be2, poolbuf, B, OUT, H, W, 2);
    }
    // ---------------- layer 3: C=128, H=W=16, OUT=256, NB=2, y=2, z=4 -------
    {
        const int H = 16, W = 16, OUT = 256;
        int npix = B * H * W;                    // 8192
        ln_prep<128, H, W><<<npix / 16, 256, 0, stream>>>(poolbuf, ln_w3, ln_b3, pnbuf, spbuf);
        kan_gemm<1152, OUT, H * W, 2, 4><<<dim3(npix / 64, 2, 4), 256, 0, stream>>>(
            pnbuf, spbuf, wt3, convbuf);           // 4 x 8.4 MB partials in convbuf
        bn_stats<<<dim3(8, OUT), 256, 0, stream>>>(convbuf, bb3, OUT, H * W, B, 4, stats3);
        long tot4 = (long)B * OUT * (H / 2) * (W / 2) / 4;  // 131072
        bn_relu_pool<<<(tot4 + 255) / 256, 256, 0, stream>>>(
            convbuf, stats3, bb3, g3, be3, (float*)d_out, B, OUT, H, W, 4);
    }
}

// Round 17
// 451.545 us; speedup vs baseline: 1.0448x; 1.0036x over previous
//
#include <hip/hip_runtime.h>

typedef _Float16 half_t;
typedef __attribute__((ext_vector_type(8))) _Float16 half8;
typedef __attribute__((ext_vector_type(4))) float floatx4;

// ---------------------------------------------------------------------------
// Round 21: R20 (best, 453.2us) + dispatch-count / round-trip reduction:
//  - ln_prep_bn<C,H,W,NZ>: fused BN+relu+2x2pool (from convbuf z-slabs +
//    stats, per-channel scale/shift in LDS) feeding the window stage of the
//    R19 two-phase ln_prep. Eliminates bn_relu_pool for layers 1,2 and the
//    poolbuf round-trip. Math order per element identical to bn_relu_pool.
//  - prep_all: 3x conv_w + stats memset in ONE dispatch.
//  16 -> 11 dispatches. gemm / bn_stats / L3 pool: unchanged (control).
// ---------------------------------------------------------------------------

#define RBF_SCALE 2.1019644f       // 1.75 * sqrt(log2 e)
#define RBF_G0   -4.2039288f       // RBF_SCALE * (-2)
#define RBF_2D    2.40224482f      // 2*sqrt(log2 e)
#define RBF_D2    1.44269504f      // log2 e
#define RBF_Q     0.13533528f      // e^-2
#define LOG2E     1.44269504f

// ---- layer-1 ln_prep (reads x directly) — R19/R20 two-phase form ----
template<int C, int H, int W>
__global__ __launch_bounds__(256)
void ln_prep(const float* __restrict__ x,
             const float* __restrict__ lnw, const float* __restrict__ lnb,
             half_t* __restrict__ pn, half_t* __restrict__ sp)
{
    const int HW = H * W, IN = C * 9, CH = IN / 8;
    const int NL = (IN + 63) / 64;
    __shared__ float xw[C * 57];
    __shared__ short offs[C * 9];
    __shared__ float2 pms[16];

    const int wv = threadIdx.x >> 6, lane = threadIdx.x & 63;
    const int pix0 = blockIdx.x * 16;
    const int b = pix0 / HW, hw0 = pix0 % HW;
    const int h = hw0 / W, x0 = hw0 % W;
    const float* xb = x + (long)b * C * HW;

    for (int idx = threadIdx.x; idx < C * 54; idx += 256) {
        int ch = idx / 54, rem = idx - ch * 54;
        int dy = rem / 18, col = rem - dy * 18;
        int y = h + dy - 1, xx = x0 + col - 1;
        float v = 0.f;
        if (y >= 0 && y < H && xx >= 0 && xx < W)
            v = xb[(long)ch * HW + y * W + xx];
        xw[ch * 57 + dy * 19 + col] = v;
    }
    for (int i = threadIdx.x; i < IN; i += 256) {
        int ch = i / 9, r = i - ch * 9;
        int dy = r / 3, dx = r - dy * 3;
        offs[i] = (short)(ch * 57 + dy * 19 + dx);
    }
    __syncthreads();

    #pragma unroll
    for (int p = 0; p < 4; ++p) {
        const int px = wv * 4 + p;
        float s = 0.f, s2 = 0.f;
        #pragma unroll
        for (int t = 0; t < NL; ++t) {
            int i = t * 64 + lane;
            if (i < IN) {
                float v = xw[offs[i] + px];
                s += v; s2 += v * v;
            }
        }
        #pragma unroll
        for (int off = 32; off > 0; off >>= 1) {
            s  += __shfl_down(s,  off, 64);
            s2 += __shfl_down(s2, off, 64);
        }
        if (lane == 0) {
            float mean = s / IN;
            float istd = rsqrtf(s2 / IN - mean * mean + 1e-5f);
            pms[px] = make_float2(mean, istd);
        }
    }
    __syncthreads();

    const int TOT = 16 * CH;
    for (int c = threadIdx.x; c < TOT; c += 256) {
        int p = c / CH, q = c - p * CH;
        float2 msv = pms[p];
        const float mean = msv.x, istd = msv.y;
        const int i0 = q * 8;
        float4 w0 = *(const float4*)(lnw + i0);
        float4 w1 = *(const float4*)(lnw + i0 + 4);
        float4 b0 = *(const float4*)(lnb + i0);
        float4 b1 = *(const float4*)(lnb + i0 + 4);
        float lw[8] = {w0.x, w0.y, w0.z, w0.w, w1.x, w1.y, w1.z, w1.w};
        float lb[8] = {b0.x, b0.y, b0.z, b0.w, b1.x, b1.y, b1.z, b1.w};
        half8 a, s8;
        #pragma unroll
        for (int e = 0; e < 8; ++e) {
            float val = xw[offs[i0 + e] + p];
            float pnv = fmaf((val - mean) * istd, lw[e], lb[e]) * RBF_SCALE;
            pnv = fminf(12.f, fmaxf(-12.f, pnv));
            a[e] = (half_t)pnv;
            float ev = __builtin_amdgcn_exp2f(-val * LOG2E);
            s8[e] = (half_t)(val * __builtin_amdgcn_rcpf(1.f + ev));
        }
        const long base = (long)(pix0 + p) * IN + i0;
        *(half8*)&pn[base] = a;
        *(half8*)&sp[base] = s8;
    }
}

// ---- fused BN+relu+pool + ln_prep for layers 2,3 ----
// conv: [NZ][32][C][2H][2W] z-partial slabs (gemm output); sums: bn_stats.
// H,W = THIS layer's (pooled) input dims. Window stage computes each pooled
// element inline: zsum -> fmaf(scale,shift) -> max over 2x2 with 0 (relu).
template<int C, int H, int W, int NZ>
__global__ __launch_bounds__(256)
void ln_prep_bn(const float* __restrict__ conv, const float* __restrict__ sums,
                const float* __restrict__ bias, const float* __restrict__ gamma,
                const float* __restrict__ beta,
                const float* __restrict__ lnw, const float* __restrict__ lnb,
                half_t* __restrict__ pn, half_t* __restrict__ sp)
{
    const int HW = H * W, IN = C * 9, CH = IN / 8;
    const int NL = (IN + 63) / 64;
    const int Hc = 2 * H, Wc = 2 * W;
    __shared__ float xw[C * 57];
    __shared__ short offs[C * 9];
    __shared__ float2 pms[16];
    __shared__ float scl[C], shf[C];

    const int wv = threadIdx.x >> 6, lane = threadIdx.x & 63;
    const int pix0 = blockIdx.x * 16;
    const int b = pix0 / HW, hw0 = pix0 % HW;
    const int h = hw0 / W, x0 = hw0 % W;

    // per-channel BN scale/shift (identical fold to bn_relu_pool)
    for (int c = threadIdx.x; c < C; c += 256) {
        float M = 32.f * Hc * Wc;
        float mean = sums[c] / M;
        float var  = sums[C + c] / M - mean * mean;
        float scale = gamma[c] * rsqrtf(var + 1e-5f);
        scl[c] = scale;
        shf[c] = beta[c] - mean * scale + bias[c] * scale;
    }
    __syncthreads();

    const long zstride = 32L * C * Hc * Wc;
    const float* cb = conv + (long)b * C * Hc * Wc;

    for (int idx = threadIdx.x; idx < C * 54; idx += 256) {
        int ch = idx / 54, rem = idx - ch * 54;
        int dy = rem / 18, col = rem - dy * 18;
        int py = h + dy - 1, px = x0 + col - 1;
        float v = 0.f;
        if (py >= 0 && py < H && px >= 0 && px < W) {
            long base = (long)ch * Hc * Wc + (long)(2 * py) * Wc + 2 * px;
            float s00 = 0.f, s01 = 0.f, s10 = 0.f, s11 = 0.f;
            #pragma unroll
            for (int z = 0; z < NZ; ++z) {
                const float* p = cb + z * zstride + base;
                float2 r0 = *(const float2*)&p[0];
                float2 r1 = *(const float2*)&p[Wc];
                s00 += r0.x; s01 += r0.y; s10 += r1.x; s11 += r1.y;
            }
            float sc = scl[ch], sh = shf[ch];
            v = fmaxf(0.f, fmaxf(fmaxf(fmaf(s00, sc, sh), fmaf(s01, sc, sh)),
                                 fmaxf(fmaf(s10, sc, sh), fmaf(s11, sc, sh))));
        }
        xw[ch * 57 + dy * 19 + col] = v;
    }
    for (int i = threadIdx.x; i < IN; i += 256) {
        int ch = i / 9, r = i - ch * 9;
        int dy = r / 3, dx = r - dy * 3;
        offs[i] = (short)(ch * 57 + dy * 19 + dx);
    }
    __syncthreads();

    #pragma unroll
    for (int p = 0; p < 4; ++p) {
        const int px = wv * 4 + p;
        float s = 0.f, s2 = 0.f;
        #pragma unroll
        for (int t = 0; t < NL; ++t) {
            int i = t * 64 + lane;
            if (i < IN) {
                float v = xw[offs[i] + px];
                s += v; s2 += v * v;
            }
        }
        #pragma unroll
        for (int off = 32; off > 0; off >>= 1) {
            s  += __shfl_down(s,  off, 64);
            s2 += __shfl_down(s2, off, 64);
        }
        if (lane == 0) {
            float mean = s / IN;
            float istd = rsqrtf(s2 / IN - mean * mean + 1e-5f);
            pms[px] = make_float2(mean, istd);
        }
    }
    __syncthreads();

    const int TOT = 16 * CH;
    for (int c = threadIdx.x; c < TOT; c += 256) {
        int p = c / CH, q = c - p * CH;
        float2 msv = pms[p];
        const float mean = msv.x, istd = msv.y;
        const int i0 = q * 8;
        float4 w0 = *(const float4*)(lnw + i0);
        float4 w1 = *(const float4*)(lnw + i0 + 4);
        float4 b0 = *(const float4*)(lnb + i0);
        float4 b1 = *(const float4*)(lnb + i0 + 4);
        float lw[8] = {w0.x, w0.y, w0.z, w0.w, w1.x, w1.y, w1.z, w1.w};
        float lb[8] = {b0.x, b0.y, b0.z, b0.w, b1.x, b1.y, b1.z, b1.w};
        half8 a, s8;
        #pragma unroll
        for (int e = 0; e < 8; ++e) {
            float val = xw[offs[i0 + e] + p];
            float pnv = fmaf((val - mean) * istd, lw[e], lb[e]) * RBF_SCALE;
            pnv = fminf(12.f, fmaxf(-12.f, pnv));
            a[e] = (half_t)pnv;
            float ev = __builtin_amdgcn_exp2f(-val * LOG2E);
            s8[e] = (half_t)(val * __builtin_amdgcn_rcpf(1.f + ev));
        }
        const long base = (long)(pix0 + p) * IN + i0;
        *(half8*)&pn[base] = a;
        *(half8*)&sp[base] = s8;
    }
}

// ---- merged weight pack (3 layers) + stats zeroing, one dispatch ----
// pack: Wt[(s*OUT + o)*64 + uu] = W[o][iblk*64 + ((uu>>3)^(o&7))*8 + (uu&7)]
__device__ __forceinline__ void pack_one(long t, int IN, int OUT,
                                         const float* __restrict__ Ws,
                                         const float* __restrict__ Wb,
                                         half_t* __restrict__ Wt)
{
    int uu = (int)(t & 63);
    long r = t >> 6;
    int o = (int)(r % OUT);
    int s = (int)(r / OUT);
    int iblk = s / 9, j = s % 9;
    int ulin = (((uu >> 3) ^ (o & 7)) << 3) + (uu & 7);
    int i = iblk * 64 + ulin;
    float v = 0.f;
    if (i < IN)
        v = (j < 8) ? Ws[(long)o * IN * 8 + i * 8 + j] : Wb[(long)o * IN + i];
    Wt[t] = (half_t)v;
}

__launch_bounds__(256)
__global__ void prep_all(const float* __restrict__ Ws1, const float* __restrict__ Wb1,
                         const float* __restrict__ Ws2, const float* __restrict__ Wb2,
                         const float* __restrict__ Ws3, const float* __restrict__ Wb3,
                         half_t* __restrict__ wt1, half_t* __restrict__ wt2,
                         half_t* __restrict__ wt3, float* __restrict__ stats)
{
    const long n1 = 64L * 27 * 64, n2 = 128L * 81 * 64, n3 = 256L * 162 * 64;
    long idx = (long)blockIdx.x * 256 + threadIdx.x;
    if (idx < 1536) stats[idx] = 0.f;           // stats1..3 contiguous
    if (idx < n1)                 pack_one(idx,            144,  64, Ws1, Wb1, wt1);
    else if (idx < n1 + n2)       pack_one(idx - n1,       576, 128, Ws2, Wb2, wt2);
    else if (idx < n1 + n2 + n3)  pack_one(idx - n1 - n2, 1152, 256, Ws3, Wb3, wt3);
}

// ---- fused A-gen + MFMA GEMM (R15 form, unchanged) ----
template<int IN, int OUT, int HW, int NB, int SPLIT>
__global__ __launch_bounds__(256)
void kan_gemm(const half_t* __restrict__ pn, const half_t* __restrict__ sp,
              const half_t* __restrict__ Wt, float* __restrict__ out)
{
    const int NIB = (IN + 63) / 64;

    __shared__ half_t As[64 * 64];
    __shared__ half_t Bs[NB * 64 * 64];

    const int tid = threadIdx.x;
    const int row = tid >> 2, q = tid & 3;
    const int pix = blockIdx.x * 64 + row;
    const half_t* pnrow = pn + (long)pix * IN;
    const half_t* sprow = sp + (long)pix * IN;

    const int wv = tid >> 6, lane = tid & 63;
    const int lr = lane & 15, lq = lane >> 4;
    const int u0 = (2 * q) ^ (row & 7);
    const int u1 = (2 * q + 1) ^ (row & 7);
    const int yoff = blockIdx.y * (4 * NB * 16);

    floatx4 acc[NB][4] = {};
    float r[16], u[16];
    half8 pf0, pf1;

    const int grpA = (blockIdx.z * NIB) / SPLIT;
    const int grpB = ((blockIdx.z + 1) * NIB) / SPLIT;
    const int s0 = grpA * 9, s1 = grpB * 9;

    int jg = 0, ibg = grpA;

    auto ldglob = [&](const half_t* base, int ib, half8& a, half8& b) {
        int i0 = ib * 64 + q * 16;
        const half_t* pp = base + ((i0 < IN) ? i0 : 0);
        a = *(const half8*)pp;
        b = *(const half8*)(pp + 8);
    };

    auto stageB = [&](int it) {
        const half_t* wsrc = Wt + (long)it * OUT * 64
                              + (long)(yoff + wv * NB * 16) * 64;
        #pragma unroll
        for (int c = 0; c < NB * 2; ++c) {
            __builtin_amdgcn_global_load_lds(
                (const __attribute__((address_space(1))) void*)(wsrc + c * 512 + lane * 8),
                (__attribute__((address_space(3))) void*)(&Bs[wv * NB * 1024 + c * 512]),
                16, 0, 0);
        }
    };

    auto genA = [&]() {
        if (jg < 8) {
            if (jg == 0) {
                #pragma unroll
                for (int kk = 0; kk < 8; ++kk) {
                    float d0 = (float)pf0[kk] - RBF_G0;
                    float d1 = (float)pf1[kk] - RBF_G0;
                    r[kk]     = __builtin_amdgcn_exp2f(-(d0 * d0));
                    u[kk]     = __builtin_amdgcn_exp2f(fmaf(RBF_2D, d0, -RBF_D2));
                    r[kk + 8] = __builtin_amdgcn_exp2f(-(d1 * d1));
                    u[kk + 8] = __builtin_amdgcn_exp2f(fmaf(RBF_2D, d1, -RBF_D2));
                }
            }
            half8 a0, a1;
            #pragma unroll
            for (int kk = 0; kk < 8; ++kk) {
                a0[kk] = (half_t)r[kk];
                a1[kk] = (half_t)r[kk + 8];
            }
            *(half8*)&As[row * 64 + u0 * 8] = a0;
            *(half8*)&As[row * 64 + u1 * 8] = a1;
            if (jg < 7) {
                #pragma unroll
                for (int kk = 0; kk < 16; ++kk) { r[kk] *= u[kk]; u[kk] *= RBF_Q; }
            }
            if (jg == 7) ldglob(sprow, ibg, pf0, pf1);
        } else {
            *(half8*)&As[row * 64 + u0 * 8] = pf0;
            *(half8*)&As[row * 64 + u1 * 8] = pf1;
            ldglob(pnrow, ibg + 1, pf0, pf1);
        }
        if (++jg == 9) { jg = 0; ++ibg; }
    };

    auto domfma = [&]() {
        __builtin_amdgcn_s_setprio(1);
        #pragma unroll
        for (int ks = 0; ks < 2; ++ks) {
            half8 af[4], bf[NB];
            #pragma unroll
            for (int mf = 0; mf < 4; ++mf) {
                int rr = mf * 16 + lr;
                af[mf] = *(const half8*)&As[rr * 64 + (((ks * 4 + lq) ^ (rr & 7)) * 8)];
            }
            #pragma unroll
            for (int nb = 0; nb < NB; ++nb) {
                int rr = wv * NB * 16 + nb * 16 + lr;
                bf[nb] = *(const half8*)&Bs[rr * 64 + (((ks * 4 + lq) ^ (rr & 7)) * 8)];
            }
            #pragma unroll
            for (int nb = 0; nb < NB; ++nb)
                #pragma unroll
                for (int mf = 0; mf < 4; ++mf)
                    acc[nb][mf] = __builtin_amdgcn_mfma_f32_16x16x32_f16(
                        bf[nb], af[mf], acc[nb][mf], 0, 0, 0);
        }
        __builtin_amdgcn_s_setprio(0);
    };

    ldglob(pnrow, grpA, pf0, pf1);

    for (int it = s0; it < s1; ++it) {
        __syncthreads();
        stageB(it);
        genA();
        __syncthreads();
        domfma();
    }

    const long zoff = (long)blockIdx.z * ((long)gridDim.x * 64) * OUT;
    #pragma unroll
    for (int nb = 0; nb < NB; ++nb)
    #pragma unroll
    for (int mf = 0; mf < 4; ++mf)
    #pragma unroll
    for (int reg = 0; reg < 4; ++reg) {
        int o  = yoff + wv * NB * 16 + nb * 16 + lq * 4 + reg;
        int p2 = blockIdx.x * 64 + mf * 16 + lr;
        int b2 = p2 / HW, hw2 = p2 % HW;
        out[zoff + ((long)b2 * OUT + o) * HW + hw2] = acc[nb][mf][reg];
    }
}

// ---- BatchNorm batch-stats over summed z-partials, float4 loads ----
__launch_bounds__(256)
__global__ void bn_stats(const float* __restrict__ h, const float* __restrict__ bias,
                         int C, int HW, int B, int nz, float* __restrict__ sums)
{
    int c = blockIdx.y;
    float bbc = bias[c];
    long zstride = (long)B * C * HW;
    int hw4 = HW / 4;
    int total4 = B * hw4;
    float s = 0.f, s2 = 0.f;
    for (int idx = blockIdx.x * 256 + threadIdx.x; idx < total4; idx += 256 * gridDim.x) {
        int b = idx / hw4, r4 = idx - b * hw4;
        long base = ((long)b * C + c) * HW + (long)r4 * 4;
        float4 a = make_float4(bbc, bbc, bbc, bbc);
        for (int z = 0; z < nz; ++z) {
            float4 p = *(const float4*)&h[z * zstride + base];
            a.x += p.x; a.y += p.y; a.z += p.z; a.w += p.w;
        }
        s  += a.x + a.y + a.z + a.w;
        s2 += a.x * a.x + a.y * a.y + a.z * a.z + a.w * a.w;
    }
    for (int off = 32; off > 0; off >>= 1) {
        s  += __shfl_down(s,  off, 64);
        s2 += __shfl_down(s2, off, 64);
    }
    __shared__ float rs[4], rs2[4];
    int lane = threadIdx.x & 63, wid = threadIdx.x >> 6;
    if (lane == 0) { rs[wid] = s; rs2[wid] = s2; }
    __syncthreads();
    if (threadIdx.x == 0) {
        atomicAdd(&sums[c],     rs[0] + rs[1] + rs[2] + rs[3]);
        atomicAdd(&sums[C + c], rs2[0] + rs2[1] + rs2[2] + rs2[3]);
    }
}

// ---- BN normalize + ReLU + 2x2 maxpool (layer 3 -> d_out only) ----
__launch_bounds__(256)
__global__ void bn_relu_pool(const float* __restrict__ h, const float* __restrict__ sums,
                             const float* __restrict__ bias,
                             const float* __restrict__ gamma, const float* __restrict__ beta,
                             float* __restrict__ out, int B, int C, int H, int W, int nz)
{
    int Ho = H / 2, Wo = W / 2, Wo4 = Wo / 4;
    long total4 = (long)B * C * Ho * Wo4;
    long idx = (long)blockIdx.x * 256 + threadIdx.x;
    if (idx >= total4) return;
    int pw4 = idx % Wo4; long t = idx / Wo4;
    int ph = t % Ho; t /= Ho;
    int c = t % C; int b = (int)(t / C);
    int pw0 = pw4 * 4;

    float M = (float)B * H * W;
    float mean = sums[c] / M;
    float var  = sums[C + c] / M - mean * mean;
    float scale = gamma[c] * rsqrtf(var + 1e-5f);
    float shift = beta[c] - mean * scale + bias[c] * scale;

    long zstride = (long)B * C * H * W;
    const float* hp = h + ((long)b * C + c) * H * W;
    long off0 = (long)(2 * ph) * W + 2 * pw0;
    long off1 = off0 + W;

    float4 r0a = make_float4(0.f, 0.f, 0.f, 0.f), r0b = r0a, r1a = r0a, r1b = r0a;
    for (int z = 0; z < nz; ++z) {
        const float* hz = hp + z * zstride;
        float4 p;
        p = *(const float4*)&hz[off0];     r0a.x += p.x; r0a.y += p.y; r0a.z += p.z; r0a.w += p.w;
        p = *(const float4*)&hz[off0 + 4]; r0b.x += p.x; r0b.y += p.y; r0b.z += p.z; r0b.w += p.w;
        p = *(const float4*)&hz[off1];     r1a.x += p.x; r1a.y += p.y; r1a.z += p.z; r1a.w += p.w;
        p = *(const float4*)&hz[off1 + 4]; r1b.x += p.x; r1b.y += p.y; r1b.z += p.z; r1b.w += p.w;
    }

    float e[8];
    e[0]=fmaf(r0a.x,scale,shift); e[1]=fmaf(r0a.y,scale,shift);
    e[2]=fmaf(r0a.z,scale,shift); e[3]=fmaf(r0a.w,scale,shift);
    e[4]=fmaf(r0b.x,scale,shift); e[5]=fmaf(r0b.y,scale,shift);
    e[6]=fmaf(r0b.z,scale,shift); e[7]=fmaf(r0b.w,scale,shift);
    float f[8];
    f[0]=fmaf(r1a.x,scale,shift); f[1]=fmaf(r1a.y,scale,shift);
    f[2]=fmaf(r1a.z,scale,shift); f[3]=fmaf(r1a.w,scale,shift);
    f[4]=fmaf(r1b.x,scale,shift); f[5]=fmaf(r1b.y,scale,shift);
    f[6]=fmaf(r1b.z,scale,shift); f[7]=fmaf(r1b.w,scale,shift);

    float4 o4;
    o4.x = fmaxf(0.f, fmaxf(fmaxf(e[0], e[1]), fmaxf(f[0], f[1])));
    o4.y = fmaxf(0.f, fmaxf(fmaxf(e[2], e[3]), fmaxf(f[2], f[3])));
    o4.z = fmaxf(0.f, fmaxf(fmaxf(e[4], e[5]), fmaxf(f[4], f[5])));
    o4.w = fmaxf(0.f, fmaxf(fmaxf(e[6], e[7]), fmaxf(f[6], f[7])));

    long obase = (((long)b * C + c) * Ho + ph) * Wo + pw0;
    *(float4*)&out[obase] = o4;
}

extern "C" void kernel_launch(void* const* d_in, const int* in_sizes, int n_in,
                              void* d_out, int out_size, void* d_ws, size_t ws_size,
                              hipStream_t stream) {
    const float* x     = (const float*)d_in[0];
    const float* ln_w1 = (const float*)d_in[1];  const float* ln_b1 = (const float*)d_in[2];
    const float* Wb1   = (const float*)d_in[3];  const float* bb1   = (const float*)d_in[4];
    const float* Ws1   = (const float*)d_in[5];  const float* g1    = (const float*)d_in[6];
    const float* be1   = (const float*)d_in[7];
    const float* ln_w2 = (const float*)d_in[8];  const float* ln_b2 = (const float*)d_in[9];
    const float* Wb2   = (const float*)d_in[10]; const float* bb2   = (const float*)d_in[11];
    const float* Ws2   = (const float*)d_in[12]; const float* g2    = (const float*)d_in[13];
    const float* be2   = (const float*)d_in[14];
    const float* ln_w3 = (const float*)d_in[15]; const float* ln_b3 = (const float*)d_in[16];
    const float* Wb3   = (const float*)d_in[17]; const float* bb3   = (const float*)d_in[18];
    const float* Ws3   = (const float*)d_in[19]; const float* g3    = (const float*)d_in[20];
    const float* be3   = (const float*)d_in[21];

    const int B = 32;
    char* ws = (char*)d_ws;
    float*  convbuf = (float*)(ws + 0);              // 33,554,432 (z-partials)
    float*  stats1  = (float*)(ws + 41943040);       //  2048 x3 (contiguous)
    float*  stats2  = (float*)(ws + 41945088);
    float*  stats3  = (float*)(ws + 41947136);
    half_t* wt1     = (half_t*)(ws + 41949184);      //   221,184
    half_t* wt2     = (half_t*)(ws + 42170368);      // 1,327,104
    half_t* wt3     = (half_t*)(ws + 43497472);      // 5,308,416
    half_t* pnbuf   = (half_t*)(ws + 48805888);      // 37,748,736
    half_t* spbuf   = (half_t*)(ws + 86554624);      // 37,748,736
    // total: 124,303,360 B

    // one dispatch: pack all 3 weight sets + zero stats
    {
        const long n = 64L*27*64 + 128L*81*64 + 256L*162*64;   // 3,428,352
        prep_all<<<(int)((n + 255) / 256), 256, 0, stream>>>(
            Ws1, Wb1, Ws2, Wb2, Ws3, Wb3, wt1, wt2, wt3, stats1);
    }

    // ---------------- layer 1: C=16, H=W=64, OUT=64, NB=1, z=1 --------------
    {
        const int H = 64, W = 64, OUT = 64;
        int npix = B * H * W;                    // 131072
        ln_prep<16, H, W><<<npix / 16, 256, 0, stream>>>(x, ln_w1, ln_b1, pnbuf, spbuf);
        kan_gemm<144, OUT, H * W, 1, 1><<<dim3(npix / 64, 1, 1), 256, 0, stream>>>(
            pnbuf, spbuf, wt1, convbuf);
        bn_stats<<<dim3(64, OUT), 256, 0, stream>>>(convbuf, bb1, OUT, H * W, B, 1, stats1);
    }
    // ---------------- layer 2: C=64, H=W=32, OUT=128, NB=2, z=2 -------------
    {
        const int H = 32, W = 32, OUT = 128;
        int npix = B * H * W;                    // 32768
        // fused BN+relu+pool (layer1 conv, nz=1) + ln_prep
        ln_prep_bn<64, H, W, 1><<<npix / 16, 256, 0, stream>>>(
            convbuf, stats1, bb1, g1, be1, ln_w2, ln_b2, pnbuf, spbuf);
        kan_gemm<576, OUT, H * W, 2, 2><<<dim3(npix / 64, 1, 2), 256, 0, stream>>>(
            pnbuf, spbuf, wt2, convbuf);           // 2 x 16.8 MB partials
        bn_stats<<<dim3(16, OUT), 256, 0, stream>>>(convbuf, bb2, OUT, H * W, B, 2, stats2);
    }
    // ---------------- layer 3: C=128, H=W=16, OUT=256, NB=2, y=2, z=4 -------
    {
        const int H = 16, W = 16, OUT = 256;
        int npix = B * H * W;                    // 8192
        // fused BN+relu+pool (layer2 conv, nz=2) + ln_prep
        ln_prep_bn<128, H, W, 2><<<npix / 16, 256, 0, stream>>>(
            convbuf, stats2, bb2, g2, be2, ln_w3, ln_b3, pnbuf, spbuf);
        kan_gemm<1152, OUT, H * W, 2, 4><<<dim3(npix / 64, 2, 4), 256, 0, stream>>>(
            pnbuf, spbuf, wt3, convbuf);           // 4 x 8.4 MB partials
        bn_stats<<<dim3(8, OUT), 256, 0, stream>>>(convbuf, bb3, OUT, H * W, B, 4, stats3);
        bn_relu_pool<<<(int)(((long)B * OUT * (H / 2) * (W / 2) / 4 + 255) / 256),
                       256, 0, stream>>>(
            convbuf, stats3, bb3, g3, be3, (float*)d_out, B, OUT, H, W, 4);
    }
}